// Round 2
// baseline (891.364 us; speedup 1.0000x reference)
//
#include <hip/hip_runtime.h>
#include <cstdio>
#include <cstdint>

typedef unsigned short u16;
typedef __attribute__((ext_vector_type(4))) unsigned short u16x4;
typedef __attribute__((ext_vector_type(8))) short short8;
typedef __attribute__((ext_vector_type(4))) float f32x4;

#define E_DIM 768
#define S_DIM 2048
#define B_DIM 8
#define F_DIM 3072
#define M_TOT (B_DIM * S_DIM) /* 16384 */

__device__ __forceinline__ u16 f2bf(float f) {
  unsigned u = __float_as_uint(f);
  u += 0x7fffu + ((u >> 16) & 1u);
  return (u16)(u >> 16);
}
__device__ __forceinline__ float bf2f(u16 b) {
  return __uint_as_float(((unsigned)b) << 16);
}

__device__ __forceinline__ void gload16(const void* g, void* l) {
  __builtin_amdgcn_global_load_lds(
      (const __attribute__((address_space(1))) void*)g,
      (__attribute__((address_space(3))) void*)l, 16, 0, 0);
}

// ---------------- f32 -> bf16 convert, 4-wide ----------------
__global__ __launch_bounds__(256) void cvt_k(const float4* __restrict__ in,
                                             u16x4* __restrict__ out, int n4) {
  int i = blockIdx.x * 256 + threadIdx.x;
  if (i >= n4) return;
  float4 f = in[i];
  u16x4 r;
  r.x = f2bf(f.x); r.y = f2bf(f.y); r.z = f2bf(f.z); r.w = f2bf(f.w);
  out[i] = r;
}

// ------- pad_mask decode: auto-detect u8 / int32 / float32 encodings -------
__global__ __launch_bounds__(1024) void decode_mask_k(const unsigned char* __restrict__ raw,
                                                      int* __restrict__ out) {
  __shared__ int s_f32, s_u8;
  int t = threadIdx.x;
  if (t == 0) { s_f32 = 0; s_u8 = 0; }
  __syncthreads();
  // Only the first 16384 bytes are guaranteed mapped (u8 case).
  const unsigned* u = (const unsigned*)raw;
  int lf = 0, lu = 0;
  for (int i = t; i < 4096; i += 1024) {
    unsigned w = u[i];
    if (w == 0x3F800000u) lf = 1;            // float 1.0 pattern
    if (w & 0xFFFFFF00u) lu = 1;             // nonzero byte at pos%4 != 0
  }
  if (lf) atomicOr(&s_f32, 1);
  if (lu) atomicOr(&s_u8, 1);
  __syncthreads();
  int mode = s_f32 ? 2 : (s_u8 ? 1 : 0);
  if (mode == 2) {
    const float* f = (const float*)raw;
    for (int i = t; i < B_DIM * S_DIM; i += 1024) out[i] = f[i] != 0.f;
  } else if (mode == 1) {
    for (int i = t; i < B_DIM * S_DIM; i += 1024) out[i] = raw[i] != 0;
  } else {
    const int* ii = (const int*)raw;
    for (int i = t; i < B_DIM * S_DIM; i += 1024) out[i] = ii[i] != 0;
  }
}

// ---------------- bf16 transpose: [Z][R=2048][C=768] -> [Z][C][R] ----------
__global__ __launch_bounds__(256) void transp_k(const u16* __restrict__ in,
                                                u16* __restrict__ out) {
  __shared__ u16 tile[32][33];
  int z = blockIdx.z;
  int c0 = blockIdx.x * 32; // E dim
  int r0 = blockIdx.y * 32; // S dim
  int tx = threadIdx.x & 31, ty = threadIdx.x >> 5;
  const u16* pin = in + (size_t)z * S_DIM * E_DIM;
  u16* pout = out + (size_t)z * E_DIM * S_DIM;
#pragma unroll
  for (int i = 0; i < 32; i += 8)
    tile[ty + i][tx] = pin[(size_t)(r0 + ty + i) * E_DIM + c0 + tx];
  __syncthreads();
#pragma unroll
  for (int i = 0; i < 32; i += 8)
    pout[(size_t)(c0 + ty + i) * S_DIM + r0 + tx] = tile[tx][ty + i];
}

// ---------------- GEMM: C[M,N] = A[M,K](bf16) * B[N,K]^T(bf16) + epilogue --
// m97 structure: 128x128 tile, BK=32, 4 waves, global_load_lds x16B,
// ds_read_b128 frags, mfma_f32_16x16x32_bf16, fp32 acc.
// RESID: 0=none, 2=bf16 residual added after relu.
template <int HAS_BIAS, int RELU, int OUTB, int RESID, int SC>
__global__ __launch_bounds__(256) void gemm_bt(
    const u16* __restrict__ A, const u16* __restrict__ Bm,
    const float* __restrict__ bias, const u16* __restrict__ residb,
    void* __restrict__ Cp, int M, int N, int K,
    long long sAz, long long sBz, long long sCz, long long sbz, float scale) {
  __shared__ alignas(16) u16 As[128 * 32];
  __shared__ alignas(16) u16 Bs[128 * 32];
  const int z = blockIdx.z;
  const u16* Ab = A + (size_t)z * sAz + (size_t)blockIdx.y * 128 * K;
  const u16* Bb = Bm + (size_t)z * sBz + (size_t)blockIdx.x * 128 * K;
  const int t = threadIdx.x;
  const int lane = t & 63;
  const int wid = t >> 6;
  const int wr = wid >> 1, wc = wid & 1;
  const int fr = lane & 15, fq = lane >> 4;

  f32x4 acc[4][4] = {};

  const int off0 = t * 16;        // byte offset within the 8KB tile
  const int off1 = off0 + 4096;
  const int r0 = off0 >> 6, c0 = off0 & 63;
  const int r1 = off1 >> 6, c1 = off1 & 63;
  const size_t rowA0 = (size_t)r0 * K * 2 + c0;
  const size_t rowA1 = (size_t)r1 * K * 2 + c1;

  for (int k0 = 0; k0 < K; k0 += 32) {
    const char* Abyte = (const char*)Ab + (size_t)k0 * 2;
    const char* Bbyte = (const char*)Bb + (size_t)k0 * 2;
    gload16(Abyte + rowA0, (char*)As + off0);
    gload16(Abyte + rowA1, (char*)As + off1);
    gload16(Bbyte + rowA0, (char*)Bs + off0);
    gload16(Bbyte + rowA1, (char*)Bs + off1);
    __syncthreads();
    short8 a[4], b[4];
#pragma unroll
    for (int m = 0; m < 4; ++m)
      a[m] = *(const short8*)(As + (wr * 64 + m * 16 + fr) * 32 + fq * 8);
#pragma unroll
    for (int n = 0; n < 4; ++n)
      b[n] = *(const short8*)(Bs + (wc * 64 + n * 16 + fr) * 32 + fq * 8);
#pragma unroll
    for (int m = 0; m < 4; ++m)
#pragma unroll
      for (int n = 0; n < 4; ++n)
        acc[m][n] = __builtin_amdgcn_mfma_f32_16x16x32_bf16(a[m], b[n], acc[m][n], 0, 0, 0);
    __syncthreads();
  }

  const size_t Cz = (size_t)z * sCz;
  const int rb = blockIdx.y * 128 + wr * 64;
  const int cb = blockIdx.x * 128 + wc * 64;
#pragma unroll
  for (int n = 0; n < 4; ++n) {
    const int col = cb + n * 16 + fr;
    float bv = 0.f;
    if (HAS_BIAS) bv = bias[(size_t)z * sbz + col];
#pragma unroll
    for (int m = 0; m < 4; ++m) {
      const int rr = rb + m * 16 + fq * 4;
#pragma unroll
      for (int j = 0; j < 4; ++j) {
        float val = acc[m][n][j];
        if (SC) val *= scale;
        if (HAS_BIAS) val += bv;
        if (RELU) val = fmaxf(val, 0.f);
        const size_t idx = Cz + (size_t)(rr + j) * N + col;
        if (RESID == 2) val += bf2f(residb[idx]);
        if (OUTB) ((u16*)Cp)[idx] = f2bf(val);
        else ((float*)Cp)[idx] = val;
      }
    }
  }
}

// ---------------- row softmax with key pad-mask, fp32 in -> bf16 out -------
__global__ __launch_bounds__(256) void smax_k(const float* __restrict__ sc,
                                              const int* __restrict__ msk,
                                              u16* __restrict__ at) {
  int row = blockIdx.x;
  const float* p = sc + (size_t)row * S_DIM;
  int t = threadIdx.x;
  float v[8];
  float mx = -3.4e38f;
#pragma unroll
  for (int i = 0; i < 8; ++i) {
    int c = t + i * 256;
    float s = p[c];
    s = (msk[c] != 0) ? -3.4e38f : s;
    v[i] = s;
    mx = fmaxf(mx, s);
  }
#pragma unroll
  for (int o = 32; o > 0; o >>= 1) mx = fmaxf(mx, __shfl_xor(mx, o));
  __shared__ float red[4];
  __shared__ float red2[4];
  int wid = t >> 6;
  if ((t & 63) == 0) red[wid] = mx;
  __syncthreads();
  mx = fmaxf(fmaxf(red[0], red[1]), fmaxf(red[2], red[3]));
  float sum = 0.f;
  float e[8];
#pragma unroll
  for (int i = 0; i < 8; ++i) {
    float ev = (v[i] < -3.0e38f) ? 0.f : __expf(v[i] - mx);
    e[i] = ev;
    sum += ev;
  }
#pragma unroll
  for (int o = 32; o > 0; o >>= 1) sum += __shfl_xor(sum, o);
  if ((t & 63) == 0) red2[wid] = sum;
  __syncthreads();
  sum = red2[0] + red2[1] + red2[2] + red2[3];
  float rs = 1.f / sum;
#pragma unroll
  for (int i = 0; i < 8; ++i) {
    int c = t + i * 256;
    at[(size_t)row * S_DIM + c] = f2bf(e[i] * rs);
  }
}

// ---------------- LayerNorm over E=768 -------------------------------------
// a: fp32 (ABF=0) or bf16 (ABF=1); optional second input b (bf16) when TWO=1.
// Outputs: fp32 (OUTF=1) and/or bf16 (OUTB=1).
template <int TWO, int ABF, int OUTF, int OUTB>
__global__ __launch_bounds__(256) void ln_k(const void* __restrict__ av,
                                            const u16* __restrict__ b,
                                            const float* __restrict__ g,
                                            const float* __restrict__ be,
                                            float* __restrict__ of,
                                            u16* __restrict__ ob) {
  int row = blockIdx.x;
  int t = threadIdx.x;
  float v[3];
  float s1 = 0.f, s2 = 0.f;
#pragma unroll
  for (int i = 0; i < 3; ++i) {
    int c = t + i * 256;
    float x;
    if (ABF) x = bf2f(((const u16*)av)[(size_t)row * E_DIM + c]);
    else x = ((const float*)av)[(size_t)row * E_DIM + c];
    if (TWO) x += bf2f(b[(size_t)row * E_DIM + c]);
    v[i] = x;
    s1 += x;
    s2 += x * x;
  }
#pragma unroll
  for (int o = 32; o > 0; o >>= 1) {
    s1 += __shfl_xor(s1, o);
    s2 += __shfl_xor(s2, o);
  }
  __shared__ float w1[4], w2[4];
  int wid = t >> 6;
  if ((t & 63) == 0) { w1[wid] = s1; w2[wid] = s2; }
  __syncthreads();
  s1 = w1[0] + w1[1] + w1[2] + w1[3];
  s2 = w2[0] + w2[1] + w2[2] + w2[3];
  const float inv = 1.f / (float)E_DIM;
  float mu = s1 * inv;
  float var = s2 * inv - mu * mu;
  float rs = rsqrtf(var + 1e-5f);
#pragma unroll
  for (int i = 0; i < 3; ++i) {
    int c = t + i * 256;
    float y = (v[i] - mu) * rs * g[c] + be[c];
    if (OUTF) of[(size_t)row * E_DIM + c] = y;
    if (OUTB) ob[(size_t)row * E_DIM + c] = f2bf(y);
  }
}

extern "C" void kernel_launch(void* const* d_in, const int* in_sizes, int n_in,
                              void* d_out, int out_size, void* d_ws, size_t ws_size,
                              hipStream_t stream) {
  (void)in_sizes; (void)n_in; (void)out_size;
  const float* x    = (const float*)d_in[0];
  const void*  mraw = d_in[1];
  const float* wq_w = (const float*)d_in[2];
  const float* wq_b = (const float*)d_in[3];
  const float* wk_w = (const float*)d_in[4];
  const float* wk_b = (const float*)d_in[5];
  const float* wv_w = (const float*)d_in[6];
  const float* wv_b = (const float*)d_in[7];
  const float* ln1g = (const float*)d_in[8];
  const float* ln1b = (const float*)d_in[9];
  const float* m1w  = (const float*)d_in[10];
  const float* m1b  = (const float*)d_in[11];
  const float* m2w  = (const float*)d_in[12];
  const float* m2b  = (const float*)d_in[13];
  const float* ln2g = (const float*)d_in[14];
  const float* ln2b = (const float*)d_in[15];
  float* outp = (float*)d_out;

  // ---- explicit workspace layout with lifetime-based aliasing ----
  char* ws = (char*)d_ws;
  const size_t SZ_W1  = (size_t)E_DIM * E_DIM * 2;       // 1,179,648
  const size_t SZ_M1W = (size_t)F_DIM * E_DIM * 2;       // 4,718,592
  const size_t SZ_XB  = (size_t)M_TOT * E_DIM * 2;       // 25,165,824
  const size_t SZ_QKV = 4 * SZ_XB;                       // 100,663,296
  const size_t SZ_ATT = (size_t)B_DIM * S_DIM * S_DIM * 2; // 67,108,864
  const size_t SZ_SC  = (size_t)S_DIM * S_DIM * 4;       // 16,777,216

  size_t o = 0;
  u16* wqb   = (u16*)(ws + o); o += SZ_W1;
  u16* wkb   = (u16*)(ws + o); o += SZ_W1;
  u16* wvb   = (u16*)(ws + o); o += SZ_W1;
  u16* m1wb  = (u16*)(ws + o); o += SZ_M1W;
  u16* m2wb  = (u16*)(ws + o); o += SZ_M1W;
  float* bias3 = (float*)(ws + o); o += 3 * E_DIM * 4;
  o = (o + 255) & ~(size_t)255;
  int* maskd = (int*)(ws + o); o += (size_t)B_DIM * S_DIM * 4;
  o = (o + 255) & ~(size_t)255;
  char* regA = ws + o; o += SZ_XB;   // xb -> h(bf16)
  char* regB = ws + o; o += SZ_QKV;  // q,k,v,vt -> hidden
  char* regC = ws + o; o += SZ_ATT;  // attn -> x1b + m2out
  char* regD = ws + o; o += SZ_SC;   // per-batch fp32 scores
  const size_t NEEDED = o;           // ~222.8 MB

  if (ws_size < NEEDED) {
    fprintf(stderr, "[kernel] ws too small: need %zu have %zu — aborting launch\n",
            NEEDED, ws_size);
    return;
  }

  u16* xb     = (u16*)regA;
  u16* h      = (u16*)regA;                       // alias: xb dead after QKV
  u16* q      = (u16*)regB;
  u16* k      = q + (size_t)M_TOT * E_DIM;
  u16* v      = k + (size_t)M_TOT * E_DIM;
  u16* vt     = v + (size_t)M_TOT * E_DIM;
  u16* hidden = (u16*)regB;                       // alias: qkv dead after PV
  u16* attn   = (u16*)regC;
  u16* x1b    = (u16*)regC;                       // alias: attn dead after PV
  u16* m2out  = x1b + (size_t)M_TOT * E_DIM;
  float* scores = (float*)regD;

  // ---- converts + bias gather + mask decode ----
  cvt_k<<<(M_TOT * E_DIM / 4 + 255) / 256, 256, 0, stream>>>((const float4*)x, (u16x4*)xb, M_TOT * E_DIM / 4);
  cvt_k<<<(E_DIM * E_DIM / 4 + 255) / 256, 256, 0, stream>>>((const float4*)wq_w, (u16x4*)wqb, E_DIM * E_DIM / 4);
  cvt_k<<<(E_DIM * E_DIM / 4 + 255) / 256, 256, 0, stream>>>((const float4*)wk_w, (u16x4*)wkb, E_DIM * E_DIM / 4);
  cvt_k<<<(E_DIM * E_DIM / 4 + 255) / 256, 256, 0, stream>>>((const float4*)wv_w, (u16x4*)wvb, E_DIM * E_DIM / 4);
  cvt_k<<<(F_DIM * E_DIM / 4 + 255) / 256, 256, 0, stream>>>((const float4*)m1w, (u16x4*)m1wb, F_DIM * E_DIM / 4);
  cvt_k<<<(E_DIM * F_DIM / 4 + 255) / 256, 256, 0, stream>>>((const float4*)m2w, (u16x4*)m2wb, E_DIM * F_DIM / 4);
  hipMemcpyAsync(bias3, wq_b, E_DIM * 4, hipMemcpyDeviceToDevice, stream);
  hipMemcpyAsync(bias3 + E_DIM, wk_b, E_DIM * 4, hipMemcpyDeviceToDevice, stream);
  hipMemcpyAsync(bias3 + 2 * E_DIM, wv_b, E_DIM * 4, hipMemcpyDeviceToDevice, stream);
  decode_mask_k<<<1, 1024, 0, stream>>>((const unsigned char*)mraw, maskd);

  // ---- QKV (batched z=3): q/k/v = x @ w^T + b ----
  gemm_bt<1, 0, 1, 0, 0><<<dim3(E_DIM / 128, M_TOT / 128, 3), 256, 0, stream>>>(
      xb, wqb, bias3, nullptr, q, M_TOT, E_DIM, E_DIM,
      0LL, (long long)E_DIM * E_DIM, (long long)M_TOT * E_DIM, E_DIM, 1.f);

  // ---- V transpose: vt[b][e][s] = v[b][s][e] ----
  transp_k<<<dim3(E_DIM / 32, S_DIM / 32, B_DIM), 256, 0, stream>>>(v, vt);

  // ---- attention: per-batch scores GEMM + masked softmax ----
  const float scl = 0.03608439182435161f; // 1/sqrt(768)
  for (int b = 0; b < B_DIM; ++b) {
    gemm_bt<0, 0, 0, 0, 1><<<dim3(S_DIM / 128, S_DIM / 128, 1), 256, 0, stream>>>(
        q + (size_t)b * S_DIM * E_DIM, k + (size_t)b * S_DIM * E_DIM, nullptr, nullptr,
        scores, S_DIM, S_DIM, E_DIM, 0LL, 0LL, 0LL, 0LL, scl);
    smax_k<<<S_DIM, 256, 0, stream>>>(scores, maskd + b * S_DIM, attn + (size_t)b * S_DIM * S_DIM);
  }

  // ---- PV (batched z=8): h = attn @ v  (vt is B^T layout), bf16 out ----
  gemm_bt<0, 0, 1, 0, 0><<<dim3(E_DIM / 128, S_DIM / 128, B_DIM), 256, 0, stream>>>(
      attn, vt, nullptr, nullptr, h, S_DIM, E_DIM, S_DIM,
      (long long)S_DIM * S_DIM, (long long)E_DIM * S_DIM, (long long)S_DIM * E_DIM, 0LL, 1.f);

  // ---- LN1: x1b = bf16(LN(x + h)) ----
  ln_k<1, 0, 0, 1><<<M_TOT, 256, 0, stream>>>(x, h, ln1g, ln1b, nullptr, x1b);

  // ---- MLP1: hidden = relu(x1b @ m1w^T + m1b), bf16 ----
  gemm_bt<1, 1, 1, 0, 0><<<dim3(F_DIM / 128, M_TOT / 128, 1), 256, 0, stream>>>(
      x1b, m1wb, m1b, nullptr, hidden, M_TOT, F_DIM, E_DIM, 0LL, 0LL, 0LL, 0LL, 1.f);

  // ---- MLP2: m2out = bf16(x1b + relu(hidden @ m2w^T + m2b)) ----
  gemm_bt<1, 1, 1, 2, 0><<<dim3(E_DIM / 128, M_TOT / 128, 1), 256, 0, stream>>>(
      hidden, m2wb, m2b, x1b, m2out, M_TOT, E_DIM, F_DIM, 0LL, 0LL, 0LL, 0LL, 1.f);

  // ---- LN2 -> fp32 out ----
  ln_k<0, 1, 1, 0><<<M_TOT, 256, 0, stream>>>(m2out, nullptr, ln2g, ln2b, outp, nullptr);
}

// Round 6
// 623.733 us; speedup vs baseline: 1.4291x; 1.4291x over previous
//
#include <hip/hip_runtime.h>
#include <cstdio>
#include <cstdint>

typedef unsigned short u16;
typedef __attribute__((ext_vector_type(4))) unsigned short u16x4;
typedef __attribute__((ext_vector_type(8))) short short8;
typedef __attribute__((ext_vector_type(4))) float f32x4;

#define E_DIM 768
#define S_DIM 2048
#define B_DIM 8
#define F_DIM 3072
#define M_TOT (B_DIM * S_DIM) /* 16384 */

__device__ __forceinline__ u16 f2bf(float f) {
  unsigned u = __float_as_uint(f);
  u += 0x7fffu + ((u >> 16) & 1u);
  return (u16)(u >> 16);
}
__device__ __forceinline__ float bf2f(u16 b) {
  return __uint_as_float(((unsigned)b) << 16);
}

__device__ __forceinline__ void gload16(const void* g, void* l) {
  __builtin_amdgcn_global_load_lds(
      (const __attribute__((address_space(1))) void*)g,
      (__attribute__((address_space(3))) void*)l, 16, 0, 0);
}

// ---------------- f32 -> bf16 convert, 4-wide ----------------
__global__ __launch_bounds__(256) void cvt_k(const float4* __restrict__ in,
                                             u16x4* __restrict__ out, int n4) {
  int i = blockIdx.x * 256 + threadIdx.x;
  if (i >= n4) return;
  float4 f = in[i];
  u16x4 r;
  r.x = f2bf(f.x); r.y = f2bf(f.y); r.z = f2bf(f.z); r.w = f2bf(f.w);
  out[i] = r;
}

// ------- pad_mask decode: auto-detect u8 / int32 / float32 encodings -------
__global__ __launch_bounds__(1024) void decode_mask_k(const unsigned char* __restrict__ raw,
                                                      int* __restrict__ out) {
  __shared__ int s_f32, s_u8;
  int t = threadIdx.x;
  if (t == 0) { s_f32 = 0; s_u8 = 0; }
  __syncthreads();
  const unsigned* u = (const unsigned*)raw;
  int lf = 0, lu = 0;
  for (int i = t; i < 4096; i += 1024) {
    unsigned w = u[i];
    if (w == 0x3F800000u) lf = 1;
    if (w & 0xFFFFFF00u) lu = 1;
  }
  if (lf) atomicOr(&s_f32, 1);
  if (lu) atomicOr(&s_u8, 1);
  __syncthreads();
  int mode = s_f32 ? 2 : (s_u8 ? 1 : 0);
  if (mode == 2) {
    const float* f = (const float*)raw;
    for (int i = t; i < B_DIM * S_DIM; i += 1024) out[i] = f[i] != 0.f;
  } else if (mode == 1) {
    for (int i = t; i < B_DIM * S_DIM; i += 1024) out[i] = raw[i] != 0;
  } else {
    const int* ii = (const int*)raw;
    for (int i = t; i < B_DIM * S_DIM; i += 1024) out[i] = ii[i] != 0;
  }
}

// ---------------- bf16 transpose: [Z][R=2048][C=768] -> [Z][C][R] ----------
__global__ __launch_bounds__(256) void transp_k(const u16* __restrict__ in,
                                                u16* __restrict__ out) {
  __shared__ u16 tile[32][33];
  int z = blockIdx.z;
  int c0 = blockIdx.x * 32;
  int r0 = blockIdx.y * 32;
  int tx = threadIdx.x & 31, ty = threadIdx.x >> 5;
  const u16* pin = in + (size_t)z * S_DIM * E_DIM;
  u16* pout = out + (size_t)z * E_DIM * S_DIM;
#pragma unroll
  for (int i = 0; i < 32; i += 8)
    tile[ty + i][tx] = pin[(size_t)(r0 + ty + i) * E_DIM + c0 + tx];
  __syncthreads();
#pragma unroll
  for (int i = 0; i < 32; i += 8)
    pout[(size_t)(c0 + ty + i) * S_DIM + r0 + tx] = tile[tx][ty + i];
}

// ============================================================================
// 256x256 / BK=64 8-phase GEMM:  C[M,N] = A[M,K](bf16) * B[N,K]^T(bf16).
// 512 thr = 8 waves (2Mx4N), per-wave 128x64 out, fp32 acc.
// LDS 128KiB: A[2buf][2half][128rows][64k], B same. T2 swizzle
// byte_col ^= ((row&7)<<4), applied as pre-swizzled GLOBAL source (linear
// gload_lds dest) + swizzled ds_read col.
// RACE-FREE staging map (every LDA/LDB consumed by same-phase MMA):
//   buf0 (even tiles) read P0-P2  -> re-staged P3-P6 (tile e+2)
//   buf1 (odd tiles)  read P4-P6  -> re-staged P7,P0,P1,P2 (tile e+3 / e+1)
// Counted vmcnt(2) at P3 (tile e+1 resident) and P7 (tile e+2 resident).
// ============================================================================
template <int HAS_BIAS, int RELU, int OUTB, int RESID, int SC>
__global__ __launch_bounds__(512, 2) void gemm256(
    const u16* __restrict__ A, const u16* __restrict__ Bm,
    const float* __restrict__ bias, const u16* __restrict__ residb,
    void* __restrict__ Cp, int M, int N, int K,
    long long sAz, long long sBz, long long sCz, long long sbz, float scale) {
  __shared__ alignas(16) char smem[131072];

  // ---- bijective XCD swizzle over flattened grid (nwg % 8 == 0 here)
  int gx = gridDim.x, gy = gridDim.y;
  int nwg = gx * gy * gridDim.z;
  int flat = blockIdx.x + gx * (blockIdx.y + gy * blockIdx.z);
  int cpx = nwg >> 3;
  int s = (flat & 7) * cpx + (flat >> 3);
  int bx = s % gx;
  int rest = s / gx;
  int by = rest % gy;
  int z = rest / gy;

  const int t = threadIdx.x;
  const int lane = t & 63;
  const int w = t >> 6;
  const int wr = w >> 2;        // 0..1  (M half)
  const int wc = w & 3;         // 0..3  (N quarter)
  const int fr = lane & 15;
  const int fq = lane >> 4;

  const int K2 = K * 2;
  const char* Ab = (const char*)(A + (size_t)z * sAz + (size_t)by * 256 * K);
  const char* Bb = (const char*)(Bm + (size_t)z * sBz + (size_t)bx * 256 * K);
  char* sA = smem;
  char* sB = smem + 65536;

  // staging per-thread constants
  const int rl0 = t >> 3;                                   // row (first gload)
  const int cbs = ((t & 7) << 4) ^ (((t >> 3) & 7) << 4);   // pre-swizzled col
  // frag-read per-lane constants (row&7 == fr&7 for all frag rows)
  const int xr = (fr & 7) << 4;
  const int cc0 = (fq * 16) ^ xr;
  const int cc1 = (64 + fq * 16) ^ xr;

  f32x4 acc[8][4] = {};
  short8 aR[4][2];
  short8 bR[2][2][2];

  // stage one half-tile (128 rows x 64 k) of operand `gb`, k-tile ct, half hf
  auto STAGE = [&](const char* gb, int ct, int hf, char* ldsbase) {
    const char* src = gb + (size_t)(hf * 128 + rl0) * K2 + ct * 128 + cbs;
    char* dst = ldsbase + hf * 16384 + t * 16;
    gload16(src, dst);
    gload16(src + (size_t)64 * K2, dst + 8192);
  };
  auto LDA = [&](int db, int mh) {
    const char* p = sA + db * 32768 + wr * 16384 + (mh * 64 + fr) * 128;
#pragma unroll
    for (int m = 0; m < 4; ++m) {
      aR[m][0] = *(const short8*)(p + m * 2048 + cc0);
      aR[m][1] = *(const short8*)(p + m * 2048 + cc1);
    }
  };
  auto LDB = [&](int db, int nh) {
    const char* p = sB + db * 32768 + (wc >> 1) * 16384 +
                    ((wc & 1) * 64 + nh * 32 + fr) * 128;
#pragma unroll
    for (int n = 0; n < 2; ++n) {
      bR[nh][n][0] = *(const short8*)(p + n * 2048 + cc0);
      bR[nh][n][1] = *(const short8*)(p + n * 2048 + cc1);
    }
  };
  auto MMA = [&](int mh, int nh) {
    __builtin_amdgcn_s_setprio(1);
#pragma unroll
    for (int m = 0; m < 4; ++m)
#pragma unroll
      for (int n = 0; n < 2; ++n) {
        acc[mh * 4 + m][nh * 2 + n] = __builtin_amdgcn_mfma_f32_16x16x32_bf16(
            aR[m][0], bR[nh][n][0], acc[mh * 4 + m][nh * 2 + n], 0, 0, 0);
        acc[mh * 4 + m][nh * 2 + n] = __builtin_amdgcn_mfma_f32_16x16x32_bf16(
            aR[m][1], bR[nh][n][1], acc[mh * 4 + m][nh * 2 + n], 0, 0, 0);
      }
    __builtin_amdgcn_s_setprio(0);
  };

  const int NT = K >> 6;  // K-tiles of 64 (always even here)

  // ---- prologue: tile0 full -> buf0; tile1.Ah0 -> buf1 (prev-P7 pattern)
  STAGE(Ab, 0, 0, sA); STAGE(Ab, 0, 1, sA);
  STAGE(Bb, 0, 0, sB); STAGE(Bb, 0, 1, sB);
  STAGE(Ab, 1, 0, sA + 32768);
  asm volatile("s_waitcnt vmcnt(2)" ::: "memory");
  __builtin_amdgcn_s_barrier();

  for (int i = 0; i < (NT >> 1); ++i) {
    const int e = 2 * i;
    const int c2 = (e + 2 < NT) ? (e + 2) : (NT - 2);  // even, valid
    const int c3 = (e + 3 < NT) ? (e + 3) : (NT - 1);  // odd, valid
    // ---- P0: tile e quad(0,0); stage (e+1).Ah1 -> buf1
    LDA(0, 0); LDB(0, 0);
    STAGE(Ab, e + 1, 1, sA + 32768);
    __builtin_amdgcn_s_barrier();
    MMA(0, 0);
    __builtin_amdgcn_s_barrier();
    // ---- P1: quad(0,1); stage (e+1).Bh0 -> buf1
    LDB(0, 1);
    STAGE(Bb, e + 1, 0, sB + 32768);
    __builtin_amdgcn_s_barrier();
    MMA(0, 1);
    __builtin_amdgcn_s_barrier();
    // ---- P2: quad(1,0); stage (e+1).Bh1 -> buf1   [last read of buf0]
    LDA(0, 1);
    STAGE(Bb, e + 1, 1, sB + 32768);
    __builtin_amdgcn_s_barrier();
    MMA(1, 0);
    __builtin_amdgcn_s_barrier();
    // ---- P3: quad(1,1); stage (e+2).Ah0 -> buf0; vmcnt(2): e+1 resident
    STAGE(Ab, c2, 0, sA);
    __builtin_amdgcn_s_barrier();
    MMA(1, 1);
    asm volatile("s_waitcnt vmcnt(2)" ::: "memory");
    __builtin_amdgcn_s_barrier();
    // ---- P4: tile e+1 quad(0,0); stage (e+2).Ah1 -> buf0
    LDA(1, 0); LDB(1, 0);
    STAGE(Ab, c2, 1, sA);
    __builtin_amdgcn_s_barrier();
    MMA(0, 0);
    __builtin_amdgcn_s_barrier();
    // ---- P5: quad(0,1); stage (e+2).Bh0 -> buf0
    LDB(1, 1);
    STAGE(Bb, c2, 0, sB);
    __builtin_amdgcn_s_barrier();
    MMA(0, 1);
    __builtin_amdgcn_s_barrier();
    // ---- P6: quad(1,0); stage (e+2).Bh1 -> buf0   [last read of buf1]
    LDA(1, 1);
    STAGE(Bb, c2, 1, sB);
    __builtin_amdgcn_s_barrier();
    MMA(1, 0);
    __builtin_amdgcn_s_barrier();
    // ---- P7: quad(1,1); stage (e+3).Ah0 -> buf1; vmcnt(2): e+2 resident
    STAGE(Ab, c3, 0, sA + 32768);
    __builtin_amdgcn_s_barrier();
    MMA(1, 1);
    asm volatile("s_waitcnt vmcnt(2)" ::: "memory");
    __builtin_amdgcn_s_barrier();
  }
  asm volatile("s_waitcnt vmcnt(0)" ::: "memory");

  // ---- epilogue
  const size_t Cz = (size_t)z * sCz;
  const int rb = by * 256 + wr * 128;
  const int cb = bx * 256 + wc * 64;
#pragma unroll
  for (int ni = 0; ni < 4; ++ni) {
    const int col = cb + (ni >> 1) * 32 + (ni & 1) * 16 + fr;
    float bv = 0.f;
    if (HAS_BIAS) bv = bias[(size_t)z * sbz + col];
#pragma unroll
    for (int mi = 0; mi < 8; ++mi) {
      const int row0 = rb + (mi >> 2) * 64 + (mi & 3) * 16 + fq * 4;
#pragma unroll
      for (int j = 0; j < 4; ++j) {
        float val = acc[mi][ni][j];
        if (SC) val *= scale;
        if (HAS_BIAS) val += bv;
        if (RELU) val = fmaxf(val, 0.f);
        const size_t idx = Cz + (size_t)(row0 + j) * N + col;
        if (RESID == 2) val += bf2f(residb[idx]);
        if (OUTB) ((u16*)Cp)[idx] = f2bf(val);
        else ((float*)Cp)[idx] = val;
      }
    }
  }
}

// ------- in-place row softmax on bf16 scores with key pad-mask -------------
__global__ __launch_bounds__(256) void smax_bf_k(u16* __restrict__ at,
                                                 const int* __restrict__ msk) {
  int row = blockIdx.x;                 // [0, 16384)
  int b = row >> 11;
  u16* p = at + (size_t)row * S_DIM;
  const int* mk = msk + (b << 11);
  int t = threadIdx.x;
  short8 sv = *(const short8*)(p + t * 8);
  float v[8];
  float mx = -3.4e38f;
#pragma unroll
  for (int i = 0; i < 8; ++i) {
    float s = bf2f((u16)sv[i]);
    if (mk[t * 8 + i] != 0) s = -3.4e38f;
    v[i] = s;
    mx = fmaxf(mx, s);
  }
#pragma unroll
  for (int o = 32; o > 0; o >>= 1) mx = fmaxf(mx, __shfl_xor(mx, o));
  __shared__ float red[4], red2[4];
  int wid = t >> 6;
  if ((t & 63) == 0) red[wid] = mx;
  __syncthreads();
  mx = fmaxf(fmaxf(red[0], red[1]), fmaxf(red[2], red[3]));
  float sum = 0.f;
  float e[8];
#pragma unroll
  for (int i = 0; i < 8; ++i) {
    float ev = (v[i] < -3.0e38f) ? 0.f : __expf(v[i] - mx);
    e[i] = ev;
    sum += ev;
  }
#pragma unroll
  for (int o = 32; o > 0; o >>= 1) sum += __shfl_xor(sum, o);
  if ((t & 63) == 0) red2[wid] = sum;
  __syncthreads();
  sum = red2[0] + red2[1] + red2[2] + red2[3];
  float rs = 1.f / sum;
  short8 ov;
#pragma unroll
  for (int i = 0; i < 8; ++i) ov[i] = (short)f2bf(e[i] * rs);
  *(short8*)(p + t * 8) = ov;
}

// ---------------- LayerNorm over E=768 -------------------------------------
template <int TWO, int ABF, int OUTF, int OUTB>
__global__ __launch_bounds__(256) void ln_k(const void* __restrict__ av,
                                            const u16* __restrict__ b,
                                            const float* __restrict__ g,
                                            const float* __restrict__ be,
                                            float* __restrict__ of,
                                            u16* __restrict__ ob) {
  int row = blockIdx.x;
  int t = threadIdx.x;
  float v[3];
  float s1 = 0.f, s2 = 0.f;
#pragma unroll
  for (int i = 0; i < 3; ++i) {
    int c = t + i * 256;
    float x;
    if (ABF) x = bf2f(((const u16*)av)[(size_t)row * E_DIM + c]);
    else x = ((const float*)av)[(size_t)row * E_DIM + c];
    if (TWO) x += bf2f(b[(size_t)row * E_DIM + c]);
    v[i] = x;
    s1 += x;
    s2 += x * x;
  }
#pragma unroll
  for (int o = 32; o > 0; o >>= 1) {
    s1 += __shfl_xor(s1, o);
    s2 += __shfl_xor(s2, o);
  }
  __shared__ float w1[4], w2[4];
  int wid = t >> 6;
  if ((t & 63) == 0) { w1[wid] = s1; w2[wid] = s2; }
  __syncthreads();
  s1 = w1[0] + w1[1] + w1[2] + w1[3];
  s2 = w2[0] + w2[1] + w2[2] + w2[3];
  const float inv = 1.f / (float)E_DIM;
  float mu = s1 * inv;
  float var = s2 * inv - mu * mu;
  float rs = rsqrtf(var + 1e-5f);
#pragma unroll
  for (int i = 0; i < 3; ++i) {
    int c = t + i * 256;
    float y = (v[i] - mu) * rs * g[c] + be[c];
    if (OUTF) of[(size_t)row * E_DIM + c] = y;
    if (OUTB) ob[(size_t)row * E_DIM + c] = f2bf(y);
  }
}

extern "C" void kernel_launch(void* const* d_in, const int* in_sizes, int n_in,
                              void* d_out, int out_size, void* d_ws, size_t ws_size,
                              hipStream_t stream) {
  (void)in_sizes; (void)n_in; (void)out_size;
  const float* x    = (const float*)d_in[0];
  const void*  mraw = d_in[1];
  const float* wq_w = (const float*)d_in[2];
  const float* wq_b = (const float*)d_in[3];
  const float* wk_w = (const float*)d_in[4];
  const float* wk_b = (const float*)d_in[5];
  const float* wv_w = (const float*)d_in[6];
  const float* wv_b = (const float*)d_in[7];
  const float* ln1g = (const float*)d_in[8];
  const float* ln1b = (const float*)d_in[9];
  const float* m1w  = (const float*)d_in[10];
  const float* m1b  = (const float*)d_in[11];
  const float* m2w  = (const float*)d_in[12];
  const float* m2b  = (const float*)d_in[13];
  const float* ln2g = (const float*)d_in[14];
  const float* ln2b = (const float*)d_in[15];
  float* outp = (float*)d_out;

  // ---- workspace layout with lifetime-based aliasing ----
  char* ws = (char*)d_ws;
  const size_t SZ_W1  = (size_t)E_DIM * E_DIM * 2;
  const size_t SZ_M1W = (size_t)F_DIM * E_DIM * 2;
  const size_t SZ_XB  = (size_t)M_TOT * E_DIM * 2;
  const size_t SZ_QKV = 4 * SZ_XB;
  const size_t SZ_ATT = (size_t)B_DIM * S_DIM * S_DIM * 2;

  size_t o = 0;
  u16* wqb   = (u16*)(ws + o); o += SZ_W1;   // wq,wk,wv contiguous (z-stride)
  o += SZ_W1;
  o += SZ_W1;
  u16* m1wb  = (u16*)(ws + o); o += SZ_M1W;
  u16* m2wb  = (u16*)(ws + o); o += SZ_M1W;
  float* bias3 = (float*)(ws + o); o += 3 * E_DIM * 4;
  o = (o + 255) & ~(size_t)255;
  int* maskd = (int*)(ws + o); o += (size_t)B_DIM * S_DIM * 4;
  o = (o + 255) & ~(size_t)255;
  char* regA = ws + o; o += SZ_XB;   // xb -> h(bf16)
  char* regB = ws + o; o += SZ_QKV;  // q,k,v,vt -> hidden
  char* regC = ws + o; o += SZ_ATT;  // scores/attn -> x1b + m2out
  const size_t NEEDED = o;           // ~206 MB

  if (ws_size < NEEDED) {
    fprintf(stderr, "[kernel] ws too small: need %zu have %zu\n", NEEDED, ws_size);
    return;
  }

  u16* wkb    = wqb + (size_t)E_DIM * E_DIM;
  u16* wvb    = wkb + (size_t)E_DIM * E_DIM;
  u16* xb     = (u16*)regA;
  u16* h      = (u16*)regA;
  u16* q      = (u16*)regB;
  u16* k      = q + (size_t)M_TOT * E_DIM;
  u16* v      = k + (size_t)M_TOT * E_DIM;
  u16* vt     = v + (size_t)M_TOT * E_DIM;
  u16* hidden = (u16*)regB;
  u16* attn   = (u16*)regC;
  u16* x1b    = (u16*)regC;
  u16* m2out  = x1b + (size_t)M_TOT * E_DIM;

  // ---- converts + bias gather + mask decode ----
  cvt_k<<<(M_TOT * E_DIM / 4 + 255) / 256, 256, 0, stream>>>((const float4*)x, (u16x4*)xb, M_TOT * E_DIM / 4);
  cvt_k<<<(E_DIM * E_DIM / 4 + 255) / 256, 256, 0, stream>>>((const float4*)wq_w, (u16x4*)wqb, E_DIM * E_DIM / 4);
  cvt_k<<<(E_DIM * E_DIM / 4 + 255) / 256, 256, 0, stream>>>((const float4*)wk_w, (u16x4*)wkb, E_DIM * E_DIM / 4);
  cvt_k<<<(E_DIM * E_DIM / 4 + 255) / 256, 256, 0, stream>>>((const float4*)wv_w, (u16x4*)wvb, E_DIM * E_DIM / 4);
  cvt_k<<<(F_DIM * E_DIM / 4 + 255) / 256, 256, 0, stream>>>((const float4*)m1w, (u16x4*)m1wb, F_DIM * E_DIM / 4);
  cvt_k<<<(E_DIM * F_DIM / 4 + 255) / 256, 256, 0, stream>>>((const float4*)m2w, (u16x4*)m2wb, E_DIM * F_DIM / 4);
  hipMemcpyAsync(bias3, wq_b, E_DIM * 4, hipMemcpyDeviceToDevice, stream);
  hipMemcpyAsync(bias3 + E_DIM, wk_b, E_DIM * 4, hipMemcpyDeviceToDevice, stream);
  hipMemcpyAsync(bias3 + 2 * E_DIM, wv_b, E_DIM * 4, hipMemcpyDeviceToDevice, stream);
  decode_mask_k<<<1, 1024, 0, stream>>>((const unsigned char*)mraw, maskd);

  // ---- QKV (batched z=3): q/k/v = x @ w^T + b ----
  gemm256<1, 0, 1, 0, 0><<<dim3(E_DIM / 256, M_TOT / 256, 3), 512, 0, stream>>>(
      xb, wqb, bias3, nullptr, q, M_TOT, E_DIM, E_DIM,
      0LL, (long long)E_DIM * E_DIM, (long long)M_TOT * E_DIM, E_DIM, 1.f);

  // ---- V transpose ----
  transp_k<<<dim3(E_DIM / 32, S_DIM / 32, B_DIM), 256, 0, stream>>>(v, vt);

  // ---- scores (batched z=8, bf16 out, scaled) -> attn buffer ----
  const float scl = 0.03608439182435161f; // 1/sqrt(768)
  gemm256<0, 0, 1, 0, 1><<<dim3(S_DIM / 256, S_DIM / 256, B_DIM), 512, 0, stream>>>(
      q, k, nullptr, nullptr, attn, S_DIM, S_DIM, E_DIM,
      (long long)S_DIM * E_DIM, (long long)S_DIM * E_DIM,
      (long long)S_DIM * S_DIM, 0LL, scl);

  // ---- masked softmax, in place on bf16 ----
  smax_bf_k<<<M_TOT, 256, 0, stream>>>(attn, maskd);

  // ---- PV (batched z=8): h = attn @ v, bf16 out ----
  gemm256<0, 0, 1, 0, 0><<<dim3(E_DIM / 256, S_DIM / 256, B_DIM), 512, 0, stream>>>(
      attn, vt, nullptr, nullptr, h, S_DIM, E_DIM, S_DIM,
      (long long)S_DIM * S_DIM, (long long)E_DIM * S_DIM, (long long)S_DIM * E_DIM, 0LL, 1.f);

  // ---- LN1: x1b = bf16(LN(x + h)) ----
  ln_k<1, 0, 0, 1><<<M_TOT, 256, 0, stream>>>(x, h, ln1g, ln1b, nullptr, x1b);

  // ---- MLP1: hidden = relu(x1b @ m1w^T + m1b), bf16 ----
  gemm256<1, 1, 1, 0, 0><<<dim3(F_DIM / 256, M_TOT / 256, 1), 512, 0, stream>>>(
      x1b, m1wb, m1b, nullptr, hidden, M_TOT, F_DIM, E_DIM, 0LL, 0LL, 0LL, 0LL, 1.f);

  // ---- MLP2: m2out = bf16(x1b + relu(hidden @ m2w^T + m2b)) ----
  gemm256<1, 1, 1, 2, 0><<<dim3(E_DIM / 256, M_TOT / 256, 1), 512, 0, stream>>>(
      hidden, m2wb, m2b, x1b, m2out, M_TOT, E_DIM, F_DIM, 0LL, 0LL, 0LL, 0LL, 1.f);

  // ---- LN2 -> fp32 out ----
  ln_k<0, 1, 1, 0><<<M_TOT, 256, 0, stream>>>(m2out, nullptr, ln2g, ln2b, outp, nullptr);
}